// Round 1
// baseline (1093.899 us; speedup 1.0000x reference)
//
#include <hip/hip_runtime.h>

#define BB 1024
#define TT 512
#define DD 64
#define HH 8

#if defined(__has_builtin)
#if __has_builtin(__builtin_amdgcn_rcpf) && __has_builtin(__builtin_amdgcn_exp2f)
#define FAST_RCP(x) __builtin_amdgcn_rcpf(x)
#define FAST_EXP2(x) __builtin_amdgcn_exp2f(x)
#endif
#endif
#ifndef FAST_RCP
#define FAST_RCP(x) (1.0f / (x))
#define FAST_EXP2(x) exp2f(x)
#endif

// One 32-lane group per batch element; lane = gate index g in [0,32).
// Gate order (torch): i=0..7, f=8..15, g=16..23, o=24..31.
// h state replicated across all 32 lanes; c held for unit j = g&7 per lane
// (4-way redundant). Encoder then decoder run back-to-back in the same wave.
__global__ __launch_bounds__(64) void seq2seq_lstm_kernel(
    const float* __restrict__ x,      // [B,T,64]
    const float* __restrict__ h0,     // [3,B,8]
    const float* __restrict__ c0,     // [3,B,8]
    const float* __restrict__ eWih0,  // [32,64]
    const float* __restrict__ eWihR,  // [2,32,8]
    const float* __restrict__ eWhh,   // [3,32,8]
    const float* __restrict__ eBih,   // [3,32]
    const float* __restrict__ eBhh,   // [3,32]
    const float* __restrict__ dWih0,  // [32,64]
    const float* __restrict__ dWihR,  // [2,32,8]
    const float* __restrict__ dWhh,   // [3,32,8]
    const float* __restrict__ dBih,   // [3,32]
    const float* __restrict__ dBhh,   // [3,32]
    const float* __restrict__ linW,   // [1,8]
    const float* __restrict__ linB,   // [1]
    float* __restrict__ out)          // [B,1]
{
    const int tid = threadIdx.x;
    const int g   = tid & 31;         // gate index within element
    const int grp = tid & 32;         // 0 or 32: group base within the wave
    const int jj  = g & 7;            // hidden unit this lane updates
    const int e   = blockIdx.x * 2 + (tid >> 5);

    // Branchless activation: tanh iff gate block == 2 (the "g" gate).
    // sigmoid(x) = rcp(1+exp2(-log2e*x)); tanh(x) = 2*rcp(1+exp2(-2*log2e*x))-1
    const bool is_tanh = ((g >> 3) == 2);
    const float s_act = is_tanh ? 2.885390082f : 1.44269504f;
    const float a_act = is_tanh ? 2.0f : 1.0f;
    const float b_act = is_tanh ? -1.0f : 0.0f;

    float hrep[3][8];   // replicated hidden state per layer
    float cc[3];        // cell state for unit jj per layer
#pragma unroll
    for (int l = 0; l < 3; ++l) {
#pragma unroll
        for (int k = 0; k < 8; ++k)
            hrep[l][k] = h0[((size_t)l * BB + e) * HH + k];
        cc[l] = c0[((size_t)l * BB + e) * HH + jj];
    }

    for (int p = 0; p < 2; ++p) {
        const float* Wih0 = p ? dWih0 : eWih0;
        const float* WihR = p ? dWihR : eWihR;
        const float* Whh  = p ? dWhh  : eWhh;
        const float* Bih  = p ? dBih  : eBih;
        const float* Bhh  = p ? dBhh  : eBhh;

        // per-lane weight rows
        float Wx[64];
#pragma unroll
        for (int k = 0; k < 64; k += 4) {
            float4 w = *(const float4*)(Wih0 + g * 64 + k);
            Wx[k] = w.x; Wx[k + 1] = w.y; Wx[k + 2] = w.z; Wx[k + 3] = w.w;
        }
        float Wh[3][8], Wi[2][8], bias[3];
#pragma unroll
        for (int l = 0; l < 3; ++l) {
#pragma unroll
            for (int k = 0; k < 8; ++k)
                Wh[l][k] = Whh[(l * 32 + g) * 8 + k];
            bias[l] = Bih[l * 32 + g] + Bhh[l * 32 + g];
        }
#pragma unroll
        for (int l = 0; l < 2; ++l)
#pragma unroll
            for (int k = 0; k < 8; ++k)
                Wi[l][k] = WihR[(l * 32 + g) * 8 + k];

        const float* xrow = x + (size_t)e * TT * DD;
        for (int t = 0; t < TT; ++t) {
            // ---------- layer 0: pre = bias + x.Wx + h0.Wh ----------
            float4 acc = make_float4(bias[0], 0.f, 0.f, 0.f);
#pragma unroll
            for (int kc = 0; kc < 16; ++kc) {
                float4 xv = *(const float4*)(xrow + kc * 4);
                acc.x = fmaf(Wx[kc * 4 + 0], xv.x, acc.x);
                acc.y = fmaf(Wx[kc * 4 + 1], xv.y, acc.y);
                acc.z = fmaf(Wx[kc * 4 + 2], xv.z, acc.z);
                acc.w = fmaf(Wx[kc * 4 + 3], xv.w, acc.w);
            }
            float pre = (acc.x + acc.y) + (acc.z + acc.w);
            {
                float r0 = 0.f, r1 = 0.f;
#pragma unroll
                for (int k = 0; k < 8; k += 2) {
                    r0 = fmaf(Wh[0][k], hrep[0][k], r0);
                    r1 = fmaf(Wh[0][k + 1], hrep[0][k + 1], r1);
                }
                pre += r0 + r1;
            }
#pragma unroll
            for (int l = 0; l < 3; ++l) {
                if (l > 0) {
                    // layers 1,2: pre = bias + h_below.Wi + h.Wh
                    float r0 = bias[l], r1 = 0.f;
#pragma unroll
                    for (int k = 0; k < 8; k += 2) {
                        r0 = fmaf(Wi[l - 1][k], hrep[l - 1][k], r0);
                        r1 = fmaf(Wi[l - 1][k + 1], hrep[l - 1][k + 1], r1);
                        r0 = fmaf(Wh[l][k], hrep[l][k], r0);
                        r1 = fmaf(Wh[l][k + 1], hrep[l][k + 1], r1);
                    }
                    pre = r0 + r1;
                }
                // activation (branchless sigmoid/tanh)
                float act = fmaf(a_act, FAST_RCP(1.0f + FAST_EXP2(-s_act * pre)), b_act);
                // gather the 4 gates for unit jj
                float iv = __shfl(act, grp + jj);
                float fv = __shfl(act, grp + 8 + jj);
                float gv = __shfl(act, grp + 16 + jj);
                float ov = __shfl(act, grp + 24 + jj);
                float cn = fmaf(fv, cc[l], iv * gv);
                cc[l] = cn;
                float e2 = FAST_EXP2(-2.885390082f * cn);
                float th = fmaf(2.0f, FAST_RCP(1.0f + e2), -1.0f);
                float hn = ov * th;
                // broadcast new h to all lanes of the group
#pragma unroll
                for (int k = 0; k < 8; ++k)
                    hrep[l][k] = __shfl(hn, grp + k);
            }
            xrow += DD;
        }
    }

    // output projection on final decoder layer-2 h
    float pred = linB[0];
#pragma unroll
    for (int k = 0; k < 8; ++k)
        pred = fmaf(linW[k], hrep[2][k], pred);
    if (g == 0)
        out[e] = pred;
}

extern "C" void kernel_launch(void* const* d_in, const int* in_sizes, int n_in,
                              void* d_out, int out_size, void* d_ws, size_t ws_size,
                              hipStream_t stream) {
    const float* x     = (const float*)d_in[0];
    const float* h0    = (const float*)d_in[1];
    const float* c0    = (const float*)d_in[2];
    const float* eWih0 = (const float*)d_in[3];
    const float* eWihR = (const float*)d_in[4];
    const float* eWhh  = (const float*)d_in[5];
    const float* eBih  = (const float*)d_in[6];
    const float* eBhh  = (const float*)d_in[7];
    const float* dWih0 = (const float*)d_in[8];
    const float* dWihR = (const float*)d_in[9];
    const float* dWhh  = (const float*)d_in[10];
    const float* dBih  = (const float*)d_in[11];
    const float* dBhh  = (const float*)d_in[12];
    const float* linW  = (const float*)d_in[13];
    const float* linB  = (const float*)d_in[14];
    float* out = (float*)d_out;

    seq2seq_lstm_kernel<<<BB / 2, 64, 0, stream>>>(
        x, h0, c0, eWih0, eWihR, eWhh, eBih, eBhh,
        dWih0, dWihR, dWhh, dBih, dBhh, linW, linB, out);
}

// Round 2
// 838.497 us; speedup vs baseline: 1.3046x; 1.3046x over previous
//
#include <hip/hip_runtime.h>

#define TT 512
#define DD 64
#define NHC 16          // steps per LDS ring chunk
#define NCHUNK 64       // 32 encoder + 32 decoder chunks
#define BB 1024

__device__ __forceinline__ float fexp2(float x){ return __builtin_amdgcn_exp2f(x); }
__device__ __forceinline__ float frcp (float x){ return __builtin_amdgcn_rcpf(x); }

// VALU-speed cross-lane move; all uses below are direction-agnostic:
// row_ror:8 = swap 8-halves of a 16-row; row_ror:4 on period-8 data;
// quad_perm broadcasts (all selectors equal).
template<int C>
__device__ __forceinline__ float dppf(float x){
  return __int_as_float(__builtin_amdgcn_update_dpp(0, __float_as_int(x), C, 0xF, 0xF, true));
}

#if defined(__has_builtin)
#if __has_builtin(__builtin_amdgcn_permlane16_swap)
#define HAVE_PLSWAP 1
#endif
#endif

// Given u whose even 16-rows hold value A and odd 16-rows hold value B
// (per 32-lane group), return ev = A in every lane, od = B in every lane.
__device__ __forceinline__ void rowpair(float u, float &ev, float &od, unsigned lane){
#ifdef HAVE_PLSWAP
  auto r = __builtin_amdgcn_permlane16_swap(__float_as_uint(u), __float_as_uint(u), false, false);
  ev = __uint_as_float(r[0]);
  od = __uint_as_float(r[1]);
#else
  float o = __shfl_xor(u, 16);
  bool hi = (lane & 16) != 0;
  ev = hi ? o : u;
  od = hi ? u : o;
#endif
}

// hn = h_{lane&7} in all 32 lanes of the group. Produce
// P[k] = h_{4u+k}, Q[k] = h_{4(1-u)+k} where u = (lane>>2)&1.
// Consumers use weights pre-swizzled by u, so no cndmasks needed.
__device__ __forceinline__ void bcast8(float hn, float P[4], float Q[4]){
  float hr = dppf<0x124>(hn);   // row_ror:4 -> h_{(j+4)&7} (direction-safe mod 8)
  P[0] = dppf<0x00>(hn); P[1] = dppf<0x55>(hn); P[2] = dppf<0xAA>(hn); P[3] = dppf<0xFF>(hn);
  Q[0] = dppf<0x00>(hr); Q[1] = dppf<0x55>(hr); Q[2] = dppf<0xAA>(hr); Q[3] = dppf<0xFF>(hr);
}

__device__ __forceinline__ float dot8(const float Wa[4], const float Wb[4],
                                      const float P[4], const float Q[4], float base){
  float r0 = fmaf(Wa[0], P[0], base);
  float r1 = Wa[1] * P[1];
  r0 = fmaf(Wa[2], P[2], r0);
  r1 = fmaf(Wa[3], P[3], r1);
  r0 = fmaf(Wb[0], Q[0], r0);
  r1 = fmaf(Wb[1], Q[1], r1);
  r0 = fmaf(Wb[2], Q[2], r0);
  r1 = fmaf(Wb[3], Q[3], r1);
  return r0 + r1;
}

// Block = 128 threads: wave0 (tid 0-63) runs the recurrence for 2 batch
// elements (32 lanes each, lane = gate index); wave1 (tid 64-127) computes
// the layer-0 input projection one chunk ahead into an LDS ring.
__global__ __launch_bounds__(128) void seq2seq_kernel(
    const float* __restrict__ x,
    const float* __restrict__ h0,
    const float* __restrict__ c0,
    const float* __restrict__ eWih0, const float* __restrict__ eWihR,
    const float* __restrict__ eWhh,  const float* __restrict__ eBih, const float* __restrict__ eBhh,
    const float* __restrict__ dWih0, const float* __restrict__ dWihR,
    const float* __restrict__ dWhh,  const float* __restrict__ dBih, const float* __restrict__ dBhh,
    const float* __restrict__ linW,  const float* __restrict__ linB,
    float* __restrict__ out)
{
  __shared__ float ring[2 * NHC * 64];   // [buf][step][sub*32+gate]
  const int tid = threadIdx.x;

  if (tid < 64) {
    // ---------------- wave0: recurrence ----------------
    const unsigned lane = (unsigned)tid;
    const int g   = lane & 31;
    const int sub = lane >> 5;
    const int e   = blockIdx.x * 2 + sub;
    const int swz = (lane & 4);            // 0 or 4: which half of h this lane's P holds
    const int typ = (g >> 3);              // 0=i,1=f,2=g(tanh),3=o
    const bool is_tanh = (typ == 2);
    const float s_act = is_tanh ? 2.885390082f : 1.44269504f;
    const float a_act = is_tanh ? 2.0f : 1.0f;
    const float b_act = is_tanh ? -1.0f : 0.0f;

    float Wha[3][4], Whb[3][4], Wia[2][4], Wib[2][4], Bs[2];
    float hd[3], cst[3], sd[3];
    float P[4], Q[4];

#pragma unroll
    for (int l = 0; l < 3; ++l) {
      hd[l]  = h0[((size_t)l * BB + e) * 8 + (g & 7)];
      cst[l] = c0[((size_t)l * BB + e) * 8 + (g & 7)];
    }

    float lWa[4], lWb[4];
#pragma unroll
    for (int k = 0; k < 4; ++k) { lWa[k] = linW[swz + k]; lWb[k] = linW[(swz ^ 4) + k]; }

    auto load_phase = [&](const float* WihR, const float* Whh,
                          const float* Bih, const float* Bhh) {
#pragma unroll
      for (int l = 0; l < 3; ++l) {
#pragma unroll
        for (int k = 0; k < 4; ++k) {
          Wha[l][k] = Whh[((l * 32) + g) * 8 + swz + k];
          Whb[l][k] = Whh[((l * 32) + g) * 8 + (swz ^ 4) + k];
        }
      }
#pragma unroll
      for (int l = 0; l < 2; ++l) {
#pragma unroll
        for (int k = 0; k < 4; ++k) {
          Wia[l][k] = WihR[((l * 32) + g) * 8 + swz + k];
          Wib[l][k] = WihR[((l * 32) + g) * 8 + (swz ^ 4) + k];
        }
        Bs[l] = Bih[(l + 1) * 32 + g] + Bhh[(l + 1) * 32 + g];
      }
      // self-recurrent dots (consumed next step); layer-0 bias lives in ring
#pragma unroll
      for (int l = 0; l < 3; ++l) {
        bcast8(hd[l], P, Q);
        sd[l] = dot8(Wha[l], Whb[l], P, Q, (l == 0) ? 0.f : Bs[l - 1]);
      }
    };

    load_phase(eWihR, eWhh, eBih, eBhh);
    __syncthreads();                       // wave1 finished filling chunk 0

    for (int cchunk = 0; cchunk < NCHUNK; ++cchunk) {
      if (cchunk == 32) load_phase(dWihR, dWhh, dBih, dBhh);  // enc -> dec
      const float* buf = ring + (cchunk & 1) * (NHC * 64);
      float pcv = buf[tid];
#pragma unroll 1
      for (int i = 0; i < NHC; ++i) {
        // prefetch next step's projection (value at i=NHC-1 is discarded)
        float pcn = buf[((i + 1) & (NHC - 1)) * 64 + tid];
        float pre = pcv + sd[0];
#pragma unroll
        for (int l = 0; l < 3; ++l) {
          float act = fmaf(a_act, frcp(1.0f + fexp2(-s_act * pre)), b_act);
          // gather i,f,g,o of unit (lane&7) into every lane: ror8 + 2 row swaps
          float r8 = dppf<0x128>(act);
          float u = (lane & 8) ? r8 : act;   // i | g per 16-row
          float v = (lane & 8) ? act : r8;   // f | o per 16-row
          float Gi, Gg, Gf, Go;
          rowpair(u, Gi, Gg, lane);
          rowpair(v, Gf, Go, lane);
          float cn = fmaf(Gf, cst[l], Gi * Gg);
          cst[l] = cn;
          float th = fmaf(2.0f, frcp(1.0f + fexp2(-2.885390082f * cn)), -1.0f);
          float hn = Go * th;
          hd[l] = hn;
          bcast8(hn, P, Q);
          if (l < 2)
            pre = dot8(Wia[l], Wib[l], P, Q, sd[l + 1]);   // next layer input
          sd[l] = dot8(Wha[l], Whb[l], P, Q, (l == 0) ? 0.f : Bs[l - 1]);
        }
        pcv = pcn;
      }
      __syncthreads();
    }

    // epilogue: P,Q hold the broadcast of the final decoder layer-2 h
    float pred = dot8(lWa, lWb, P, Q, linB[0]);
    if (g == 0) out[e] = pred;

  } else {
    // ---------------- wave1: layer-0 input projector ----------------
    const int l64  = tid - 64;
    const int gate = l64 & 31;
    const int sub  = l64 >> 5;
    const int e    = blockIdx.x * 2 + sub;
    float Wx[64];
    float b0v;

    auto load_wx = [&](const float* Wih0, const float* Bih, const float* Bhh) {
#pragma unroll
      for (int k = 0; k < 16; ++k) {
        float4 w = *(const float4*)(Wih0 + gate * 64 + k * 4);
        Wx[k * 4 + 0] = w.x; Wx[k * 4 + 1] = w.y;
        Wx[k * 4 + 2] = w.z; Wx[k * 4 + 3] = w.w;
      }
      b0v = Bih[gate] + Bhh[gate];
    };

    auto fill = [&](int fc) {
      const int tb = (fc & 31) * NHC;
      float* dst = ring + (fc & 1) * (NHC * 64) + l64;
      const float* xr = x + ((size_t)e * TT + tb) * DD;
#pragma unroll 1
      for (int i = 0; i < NHC; ++i) {
        float a0 = b0v, a1 = 0.f, a2 = 0.f, a3 = 0.f;
#pragma unroll
        for (int kc = 0; kc < 16; ++kc) {
          float4 xq = *(const float4*)(xr + kc * 4);
          a0 = fmaf(Wx[kc * 4 + 0], xq.x, a0);
          a1 = fmaf(Wx[kc * 4 + 1], xq.y, a1);
          a2 = fmaf(Wx[kc * 4 + 2], xq.z, a2);
          a3 = fmaf(Wx[kc * 4 + 3], xq.w, a3);
        }
        dst[i * 64] = (a0 + a1) + (a2 + a3);
        xr += DD;
      }
    };

    load_wx(eWih0, eBih, eBhh);
    fill(0);
    __syncthreads();
    for (int cchunk = 0; cchunk < NCHUNK; ++cchunk) {
      int fc = cchunk + 1;
      if (fc < NCHUNK) {
        if (fc == 32) load_wx(dWih0, dBih, dBhh);   // decoder weights
        fill(fc);
      }
      __syncthreads();
    }
  }
}

extern "C" void kernel_launch(void* const* d_in, const int* in_sizes, int n_in,
                              void* d_out, int out_size, void* d_ws, size_t ws_size,
                              hipStream_t stream) {
  const float* x     = (const float*)d_in[0];
  const float* h0    = (const float*)d_in[1];
  const float* c0    = (const float*)d_in[2];
  const float* eWih0 = (const float*)d_in[3];
  const float* eWihR = (const float*)d_in[4];
  const float* eWhh  = (const float*)d_in[5];
  const float* eBih  = (const float*)d_in[6];
  const float* eBhh  = (const float*)d_in[7];
  const float* dWih0 = (const float*)d_in[8];
  const float* dWihR = (const float*)d_in[9];
  const float* dWhh  = (const float*)d_in[10];
  const float* dBih  = (const float*)d_in[11];
  const float* dBhh  = (const float*)d_in[12];
  const float* linW  = (const float*)d_in[13];
  const float* linB  = (const float*)d_in[14];
  float* out = (float*)d_out;

  seq2seq_kernel<<<BB / 2, 128, 0, stream>>>(
      x, h0, c0, eWih0, eWihR, eWhh, eBih, eBhh,
      dWih0, dWihR, dWhh, dBih, dBhh, linW, linB, out);
}

// Round 3
// 680.749 us; speedup vs baseline: 1.6069x; 1.2317x over previous
//
#include <hip/hip_runtime.h>

#define TT 512
#define DD 64
#define NHC 16          // steps per LDS ring chunk
#define NCHUNK 64       // 32 encoder + 32 decoder chunks
#define BB 1024

__device__ __forceinline__ float fexp2(float x){ return __builtin_amdgcn_exp2f(x); }
__device__ __forceinline__ float frcp (float x){ return __builtin_amdgcn_rcpf(x); }

// VALU-speed cross-lane; all uses direction-agnostic (swap-by-8, ror4 on
// period-8 data, uniform quad_perm broadcasts).
template<int C>
__device__ __forceinline__ float dppf(float x){
  return __int_as_float(__builtin_amdgcn_update_dpp(0, __float_as_int(x), C, 0xF, 0xF, true));
}

#if defined(__has_builtin)
#if __has_builtin(__builtin_amdgcn_permlane16_swap)
#define HAVE_PLSWAP 1
#endif
#endif

__device__ __forceinline__ void rowpair(float u, float &ev, float &od, unsigned lane){
#ifdef HAVE_PLSWAP
  auto r = __builtin_amdgcn_permlane16_swap(__float_as_uint(u), __float_as_uint(u), false, false);
  ev = __uint_as_float(r[0]);
  od = __uint_as_float(r[1]);
#else
  float o = __shfl_xor(u, 16);
  bool hi = (lane & 16) != 0;
  ev = hi ? o : u;
  od = hi ? u : o;
#endif
}

__device__ __forceinline__ void bcast8(float hn, float P[4], float Q[4]){
  float hr = dppf<0x124>(hn);   // row_ror:4 -> h_{(j+4)&7}
  P[0] = dppf<0x00>(hn); P[1] = dppf<0x55>(hn); P[2] = dppf<0xAA>(hn); P[3] = dppf<0xFF>(hn);
  Q[0] = dppf<0x00>(hr); Q[1] = dppf<0x55>(hr); Q[2] = dppf<0xAA>(hr); Q[3] = dppf<0xFF>(hr);
}

__device__ __forceinline__ float dot8(const float Wa[4], const float Wb[4],
                                      const float P[4], const float Q[4], float base){
  float r0 = fmaf(Wa[0], P[0], base);
  float r1 = Wa[1] * P[1];
  r0 = fmaf(Wa[2], P[2], r0);
  r1 = fmaf(Wa[3], P[3], r1);
  r0 = fmaf(Wb[0], Q[0], r0);
  r1 = fmaf(Wb[1], Q[1], r1);
  r0 = fmaf(Wb[2], Q[2], r0);
  r1 = fmaf(Wb[3], Q[3], r1);
  return r0 + r1;
}

template<int N> struct IC { static constexpr int v = N; };

// Block = 192 threads: wave0 runs the skewed 3-layer recurrence for 2 batch
// elements; waves 1,2 compute the layer-0 input projection one chunk ahead
// into the LDS ring (8 steps each).
__global__ __launch_bounds__(192, 2) void seq2seq_kernel(
    const float* __restrict__ x,
    const float* __restrict__ h0,
    const float* __restrict__ c0,
    const float* __restrict__ eWih0, const float* __restrict__ eWihR,
    const float* __restrict__ eWhh,  const float* __restrict__ eBih, const float* __restrict__ eBhh,
    const float* __restrict__ dWih0, const float* __restrict__ dWihR,
    const float* __restrict__ dWhh,  const float* __restrict__ dBih, const float* __restrict__ dBhh,
    const float* __restrict__ linW,  const float* __restrict__ linB,
    float* __restrict__ out)
{
  __shared__ float ring[2 * NHC * 64];
  const int tid = threadIdx.x;

  if (tid < 64) {
    // ---------------- wave0: skewed recurrence ----------------
    const unsigned lane = (unsigned)tid;
    const int g   = lane & 31;
    const int sub = lane >> 5;
    const int e   = blockIdx.x * 2 + sub;
    const int swz = (lane & 4);
    const bool is_tanh = ((g >> 3) == 2);
    const float s_act = is_tanh ? 2.885390082f : 1.44269504f;
    const float a_act = is_tanh ? 2.0f : 1.0f;
    const float b_act = is_tanh ? -1.0f : 0.0f;

    float Wha[3][4], Whb[3][4], Wia[2][4], Wib[2][4], Bs[2];
    float hd[3], cst[3], sd[3];
    float c1 = 0.f, c2 = 0.f;

#pragma unroll
    for (int l = 0; l < 3; ++l) {
      hd[l]  = h0[((size_t)l * BB + e) * 8 + (g & 7)];
      cst[l] = c0[((size_t)l * BB + e) * 8 + (g & 7)];
    }

    auto load_phase = [&](const float* WihR, const float* Whh,
                          const float* Bih, const float* Bhh) {
#pragma unroll
      for (int l = 0; l < 3; ++l) {
#pragma unroll
        for (int k = 0; k < 4; ++k) {
          Wha[l][k] = Whh[((l * 32) + g) * 8 + swz + k];
          Whb[l][k] = Whh[((l * 32) + g) * 8 + (swz ^ 4) + k];
        }
      }
#pragma unroll
      for (int l = 0; l < 2; ++l) {
#pragma unroll
        for (int k = 0; k < 4; ++k) {
          Wia[l][k] = WihR[((l * 32) + g) * 8 + swz + k];
          Wib[l][k] = WihR[((l * 32) + g) * 8 + (swz ^ 4) + k];
        }
        Bs[l] = Bih[(l + 1) * 32 + g] + Bhh[(l + 1) * 32 + g];
      }
#pragma unroll
      for (int l = 0; l < 3; ++l) {
        float P[4], Q[4];
        bcast8(hd[l], P, Q);
        sd[l] = dot8(Wha[l], Whb[l], P, Q, (l == 0) ? 0.f : Bs[l - 1]);
      }
    };

    // one LSTM cell step for layer l; returns next-layer input contribution
    auto lstep = [&](auto L, float in) -> float {
      constexpr int l = decltype(L)::v;
      float pre = in + sd[l];
      float act = fmaf(a_act, frcp(1.0f + fexp2(-s_act * pre)), b_act);
      float r8 = dppf<0x128>(act);
      float u = (lane & 8) ? r8 : act;
      float v = (lane & 8) ? act : r8;
      float Gi, Gg, Gf, Go;
      rowpair(u, Gi, Gg, lane);
      rowpair(v, Gf, Go, lane);
      float cn = fmaf(Gf, cst[l], Gi * Gg);
      cst[l] = cn;
      float th = fmaf(2.0f, frcp(1.0f + fexp2(-2.885390082f * cn)), -1.0f);
      float hn = Go * th;
      hd[l] = hn;
      float P[4], Q[4];
      bcast8(hn, P, Q);
      sd[l] = dot8(Wha[l], Whb[l], P, Q, (l == 0) ? 0.f : Bs[l - 1]);
      if constexpr (l < 2)
        return dot8(Wia[l], Wib[l], P, Q, 0.f);
      else
        return 0.f;
    };

    // one chunk = 16 skewed iterations. PEELED=1 guards the first 2 iters
    // of a phase (layers 1,2 not yet started). Hot chunks are branch-free.
    auto run_chunk = [&](auto PEELED, const float* buf) {
      constexpr bool PE = (decltype(PEELED)::v != 0);
      float pcv = buf[tid];
#pragma unroll 1
      for (int i = 0; i < NHC; ++i) {
        float pcn = buf[((i + 1) & (NHC - 1)) * 64 + tid];
        float n1 = lstep(IC<0>{}, pcv);
        float n2 = 0.f;
        if (!PE || i >= 1) n2 = lstep(IC<1>{}, c1);
        if (!PE || i >= 2) (void)lstep(IC<2>{}, c2);
        c1 = n1; c2 = n2;
        pcv = pcn;
      }
    };

    load_phase(eWihR, eWhh, eBih, eBhh);
    __syncthreads();                         // chunk 0 ready

#pragma unroll 1
    for (int ph = 0; ph < 2; ++ph) {
      if (ph == 1) load_phase(dWihR, dWhh, dBih, dBhh);
      const int cbase = ph * 32;
      run_chunk(IC<1>{}, ring + (cbase & 1) * (NHC * 64));
      __syncthreads();
#pragma unroll 1
      for (int cc = 1; cc < 32; ++cc) {
        run_chunk(IC<0>{}, ring + ((cbase + cc) & 1) * (NHC * 64));
        __syncthreads();
      }
      // drain the skew: layer1 step 511, layer2 steps 510, 511
      float d1 = lstep(IC<1>{}, c1);
      (void)lstep(IC<2>{}, c2);
      (void)lstep(IC<2>{}, d1);
    }

    // epilogue: linear on final decoder layer-2 h
    float lWa[4], lWb[4];
#pragma unroll
    for (int k = 0; k < 4; ++k) { lWa[k] = linW[swz + k]; lWb[k] = linW[(swz ^ 4) + k]; }
    float P[4], Q[4];
    bcast8(hd[2], P, Q);
    float pred = dot8(lWa, lWb, P, Q, linB[0]);
    if (g == 0) out[e] = pred;

  } else {
    // ---------------- waves 1,2: layer-0 input projectors ----------------
    const int l64  = (tid - 64) & 63;
    const int w    = (tid - 64) >> 6;        // 0 or 1: which projector wave
    const int gate = l64 & 31;
    const int sub  = l64 >> 5;
    const int e    = blockIdx.x * 2 + sub;
    float Wx[64];
    float b0v;

    auto load_wx = [&](const float* Wih0, const float* Bih, const float* Bhh) {
#pragma unroll
      for (int k = 0; k < 16; ++k) {
        float4 wq = *(const float4*)(Wih0 + gate * 64 + k * 4);
        Wx[k * 4 + 0] = wq.x; Wx[k * 4 + 1] = wq.y;
        Wx[k * 4 + 2] = wq.z; Wx[k * 4 + 3] = wq.w;
      }
      b0v = Bih[gate] + Bhh[gate];
    };

    auto fill = [&](int fc) {
      const int tb = (fc & 31) * NHC + w * 8;
      float* dst = ring + (fc & 1) * (NHC * 64) + (w * 8) * 64 + l64;
      const float* xr = x + ((size_t)e * TT + tb) * DD;
#pragma unroll 2
      for (int i = 0; i < 8; ++i) {
        float a0 = b0v, a1 = 0.f, a2 = 0.f, a3 = 0.f;
#pragma unroll
        for (int kc = 0; kc < 16; ++kc) {
          float4 xq = *(const float4*)(xr + kc * 4);
          a0 = fmaf(Wx[kc * 4 + 0], xq.x, a0);
          a1 = fmaf(Wx[kc * 4 + 1], xq.y, a1);
          a2 = fmaf(Wx[kc * 4 + 2], xq.z, a2);
          a3 = fmaf(Wx[kc * 4 + 3], xq.w, a3);
        }
        dst[i * 64] = (a0 + a1) + (a2 + a3);
        xr += DD;
      }
    };

    load_wx(eWih0, eBih, eBhh);
    fill(0);
    __syncthreads();
#pragma unroll 1
    for (int cc = 0; cc < NCHUNK; ++cc) {
      int fc = cc + 1;
      if (fc < NCHUNK) {
        if (fc == 32) load_wx(dWih0, dBih, dBhh);
        fill(fc);
      }
      __syncthreads();
    }
  }
}

extern "C" void kernel_launch(void* const* d_in, const int* in_sizes, int n_in,
                              void* d_out, int out_size, void* d_ws, size_t ws_size,
                              hipStream_t stream) {
  const float* x     = (const float*)d_in[0];
  const float* h0    = (const float*)d_in[1];
  const float* c0    = (const float*)d_in[2];
  const float* eWih0 = (const float*)d_in[3];
  const float* eWihR = (const float*)d_in[4];
  const float* eWhh  = (const float*)d_in[5];
  const float* eBih  = (const float*)d_in[6];
  const float* eBhh  = (const float*)d_in[7];
  const float* dWih0 = (const float*)d_in[8];
  const float* dWihR = (const float*)d_in[9];
  const float* dWhh  = (const float*)d_in[10];
  const float* dBih  = (const float*)d_in[11];
  const float* dBhh  = (const float*)d_in[12];
  const float* linW  = (const float*)d_in[13];
  const float* linB  = (const float*)d_in[14];
  float* out = (float*)d_out;

  seq2seq_kernel<<<BB / 2, 192, 0, stream>>>(
      x, h0, c0, eWih0, eWihR, eWhh, eBih, eBhh,
      dWih0, dWihR, dWhh, dBih, dBhh, linW, linB, out);
}